// Round 1
// baseline (5117.892 us; speedup 1.0000x reference)
//
#include <hip/hip_runtime.h>
#include <cstddef>

#define T_     8000
#define L_     803
#define C_     256
#define D_     512
#define NB_    32
#define FK_    20
#define NBATCH 4
#define EPS_   1e-5f

// -------- fold BN params: scale = g*rsqrt(v+eps), bias = b - m*scale --------
__global__ __launch_bounds__(256) void bn_precompute(
    const float* __restrict__ g, const float* __restrict__ b,
    const float* __restrict__ m, const float* __restrict__ v,
    float* __restrict__ scale, float* __restrict__ bias, int n) {
  int i = blockIdx.x * blockDim.x + threadIdx.x;
  if (i >= n) return;
  float s = g[i] * rsqrtf(v[i] + EPS_);
  scale[i] = s;
  bias[i] = b[i] - m[i] * s;
}

// -------- encoder: Conv1d(1->256, k=20, stride=10, pad=20) --------
__global__ __launch_bounds__(256) void enc_kernel(
    const float* __restrict__ x, const float* __restrict__ w_enc,
    float* __restrict__ xe, float* __restrict__ h) {
  int idx = blockIdx.x * blockDim.x + threadIdx.x;
  if (idx >= NBATCH * C_ * L_) return;
  int l = idx % L_;
  int c = (idx / L_) % C_;
  int n = idx / (L_ * C_);
  const float* xn = x + (size_t)n * T_;
  const float* w = w_enc + c * FK_;
  int t0 = l * 10 - 20;
  float acc = 0.f;
#pragma unroll
  for (int k = 0; k < FK_; k++) {
    int t = t0 + k;
    float xv = (t >= 0 && t < T_) ? xn[t] : 0.f;
    acc = fmaf(xv, w[k], acc);
  }
  xe[idx] = acc;
  h[idx] = acc;
}

// -------- stage1: z = BN2( W1 @ BN1(h) )   GEMM M=512(d) K=256(c) N=803(l) per n
__global__ __launch_bounds__(256) void stage1_gemm(
    const float* __restrict__ h, const float* __restrict__ w1i,
    const float* __restrict__ s1, const float* __restrict__ bb1,
    const float* __restrict__ s2, const float* __restrict__ bb2,
    float* __restrict__ z) {
  const int l0 = blockIdx.x * 64;
  const int d0 = blockIdx.y * 64;
  const int n = blockIdx.z;
  const int tid = threadIdx.x;

  __shared__ float As[32][64];  // [k][m]  (W1 transposed)
  __shared__ float Bs[32][64];  // [k][l]  (BN1(h))

  float acc[4][4] = {{0.f, 0.f, 0.f, 0.f}};
  const int tm = (tid & 15) * 4;
  const int tn = (tid >> 4) * 4;
  const float* hn = h + (size_t)n * C_ * L_;

  const int colB = tid & 63;
  const int rB0 = tid >> 6;
  const int lB = l0 + colB;
  const bool lv = lB < L_;

  for (int k0 = 0; k0 < C_; k0 += 32) {
    // A tile: w1i[d0+r][k0+c], 64x32, float4 loads, store transposed
#pragma unroll
    for (int q = 0; q < 2; q++) {
      int ff = tid * 2 + q;
      int r = ff >> 3;
      int c4 = (ff & 7) * 4;
      float4 a = *reinterpret_cast<const float4*>(w1i + (size_t)(d0 + r) * C_ + k0 + c4);
      As[c4 + 0][r] = a.x;
      As[c4 + 1][r] = a.y;
      As[c4 + 2][r] = a.z;
      As[c4 + 3][r] = a.w;
    }
    // B tile: BN1(h[n][k0+r][l0+col]), 32x64
#pragma unroll
    for (int q = 0; q < 8; q++) {
      int r = rB0 + q * 4;
      int c = k0 + r;
      float val = lv ? hn[(size_t)c * L_ + lB] : 0.f;
      Bs[r][colB] = fmaf(val, s1[c], bb1[c]);
    }
    __syncthreads();
#pragma unroll
    for (int kk = 0; kk < 32; kk++) {
      float4 a = *reinterpret_cast<const float4*>(&As[kk][tm]);
      float4 b = *reinterpret_cast<const float4*>(&Bs[kk][tn]);
      float av[4] = {a.x, a.y, a.z, a.w};
      float bv[4] = {b.x, b.y, b.z, b.w};
#pragma unroll
      for (int mi = 0; mi < 4; mi++)
#pragma unroll
        for (int ni = 0; ni < 4; ni++)
          acc[mi][ni] = fmaf(av[mi], bv[ni], acc[mi][ni]);
    }
    __syncthreads();
  }
  float* zn = z + (size_t)n * D_ * L_;
#pragma unroll
  for (int mi = 0; mi < 4; mi++) {
    int d = d0 + tm + mi;
    float sc = s2[d], bi = bb2[d];
#pragma unroll
    for (int ni = 0; ni < 4; ni++) {
      int l = l0 + tn + ni;
      if (l < L_) zn[(size_t)d * L_ + l] = fmaf(acc[mi][ni], sc, bi);
    }
  }
}

// -------- stage2: h += W2 @ BN3( dconv(z) )   GEMM M=256(c) K=512(d) N=803(l)
__global__ __launch_bounds__(256) void stage2_gemm(
    float* __restrict__ h, const float* __restrict__ z,
    const float* __restrict__ w2i, const float* __restrict__ wdi,
    const float* __restrict__ s3, const float* __restrict__ bb3,
    int dil) {
  const int l0 = blockIdx.x * 64;
  const int c0 = blockIdx.y * 64;
  const int n = blockIdx.z;
  const int tid = threadIdx.x;

  __shared__ float As[32][64];  // [k][m]  (W2 transposed)
  __shared__ float Bs[32][64];  // [k][l]  (BN3(dconv(z)))

  float acc[4][4] = {{0.f, 0.f, 0.f, 0.f}};
  const int tm = (tid & 15) * 4;
  const int tn = (tid >> 4) * 4;
  const float* zn = z + (size_t)n * D_ * L_;

  const int colB = tid & 63;
  const int rB0 = tid >> 6;
  const int lB = l0 + colB;
  const bool lv = lB < L_;

  for (int k0 = 0; k0 < D_; k0 += 32) {
    // A tile: w2i[c0+r][k0+c], 64x32
#pragma unroll
    for (int q = 0; q < 2; q++) {
      int ff = tid * 2 + q;
      int r = ff >> 3;
      int c4 = (ff & 7) * 4;
      float4 a = *reinterpret_cast<const float4*>(w2i + (size_t)(c0 + r) * D_ + k0 + c4);
      As[c4 + 0][r] = a.x;
      As[c4 + 1][r] = a.y;
      As[c4 + 2][r] = a.z;
      As[c4 + 3][r] = a.w;
    }
    // B tile: BN3( dilated depthwise conv of z )[k0+r][l0+col]
#pragma unroll
    for (int q = 0; q < 8; q++) {
      int r = rB0 + q * 4;
      int d = k0 + r;
      const float* zd = zn + (size_t)d * L_;
      const float* wd = wdi + d * 3;
      float vout = 0.f;
      if (lv) {
        float m = zd[lB] * wd[1];
        if (lB - dil >= 0) m = fmaf(zd[lB - dil], wd[0], m);
        if (lB + dil < L_) m = fmaf(zd[lB + dil], wd[2], m);
        vout = fmaf(m, s3[d], bb3[d]);
      }
      Bs[r][colB] = vout;
    }
    __syncthreads();
#pragma unroll
    for (int kk = 0; kk < 32; kk++) {
      float4 a = *reinterpret_cast<const float4*>(&As[kk][tm]);
      float4 b = *reinterpret_cast<const float4*>(&Bs[kk][tn]);
      float av[4] = {a.x, a.y, a.z, a.w};
      float bv[4] = {b.x, b.y, b.z, b.w};
#pragma unroll
      for (int mi = 0; mi < 4; mi++)
#pragma unroll
        for (int ni = 0; ni < 4; ni++)
          acc[mi][ni] = fmaf(av[mi], bv[ni], acc[mi][ni]);
    }
    __syncthreads();
  }
  float* hn = h + (size_t)n * C_ * L_;
#pragma unroll
  for (int mi = 0; mi < 4; mi++) {
    int c = c0 + tm + mi;
#pragma unroll
    for (int ni = 0; ni < 4; ni++) {
      int l = l0 + tn + ni;
      if (l < L_) hn[(size_t)c * L_ + l] += acc[mi][ni];
    }
  }
}

// -------- mask: y = xe * sigmoid(h) --------
__global__ __launch_bounds__(256) void mask_kernel(
    const float* __restrict__ xe, const float* __restrict__ h,
    float* __restrict__ y, int total) {
  int i = blockIdx.x * blockDim.x + threadIdx.x;
  if (i >= total) return;
  float hv = h[i];
  y[i] = xe[i] / (1.f + expf(-hv));
}

// -------- decoder: ConvTranspose1d(C->1, k=20, s=10), slice [20:8020] --------
__global__ __launch_bounds__(256) void dec_kernel(
    const float* __restrict__ y, const float* __restrict__ w_dec,
    float* __restrict__ out) {
  int idx = blockIdx.x * blockDim.x + threadIdx.x;
  if (idx >= NBATCH * T_) return;
  int t = idx % T_;
  int n = idx / T_;
  int tt = t + FK_;
  int l0 = tt / 10;     // in [2, 801]
  int k0 = tt % 10;
  const float* yn = y + (size_t)n * C_ * L_;
  float acc = 0.f;
  for (int c = 0; c < C_; c++) {
    const float* yr = yn + (size_t)c * L_;
    const float* wr = w_dec + c * FK_;
    acc = fmaf(yr[l0], wr[k0], acc);
    acc = fmaf(yr[l0 - 1], wr[k0 + 10], acc);
  }
  out[idx] = acc;
}

extern "C" void kernel_launch(void* const* d_in, const int* in_sizes, int n_in,
                              void* d_out, int out_size, void* d_ws, size_t ws_size,
                              hipStream_t stream) {
  const float* x     = (const float*)d_in[0];
  const float* w_enc = (const float*)d_in[1];
  const float* w1    = (const float*)d_in[2];
  const float* wd    = (const float*)d_in[3];
  const float* w2    = (const float*)d_in[4];
  const float* w_dec = (const float*)d_in[5];
  const float* bn1g = (const float*)d_in[6],  *bn1b = (const float*)d_in[7],
             * bn1m = (const float*)d_in[8],  *bn1v = (const float*)d_in[9];
  const float* bn2g = (const float*)d_in[10], *bn2b = (const float*)d_in[11],
             * bn2m = (const float*)d_in[12], *bn2v = (const float*)d_in[13];
  const float* bn3g = (const float*)d_in[14], *bn3b = (const float*)d_in[15],
             * bn3m = (const float*)d_in[16], *bn3v = (const float*)d_in[17];
  float* out = (float*)d_out;

  float* ws = (float*)d_ws;
  float* xe = ws;                                  // N*C*L
  float* h  = xe + (size_t)NBATCH * C_ * L_;       // N*C*L
  float* z  = h  + (size_t)NBATCH * C_ * L_;       // N*D*L
  float* s1 = z  + (size_t)NBATCH * D_ * L_;       // NB*C
  float* b1 = s1 + NB_ * C_;
  float* s2 = b1 + NB_ * C_;                       // NB*D
  float* b2 = s2 + NB_ * D_;
  float* s3 = b2 + NB_ * D_;
  float* b3 = s3 + NB_ * D_;
  float* y  = z;  // reuse z region after residual blocks finish

  bn_precompute<<<(NB_ * C_ + 255) / 256, 256, 0, stream>>>(bn1g, bn1b, bn1m, bn1v, s1, b1, NB_ * C_);
  bn_precompute<<<(NB_ * D_ + 255) / 256, 256, 0, stream>>>(bn2g, bn2b, bn2m, bn2v, s2, b2, NB_ * D_);
  bn_precompute<<<(NB_ * D_ + 255) / 256, 256, 0, stream>>>(bn3g, bn3b, bn3m, bn3v, s3, b3, NB_ * D_);

  enc_kernel<<<(NBATCH * C_ * L_ + 255) / 256, 256, 0, stream>>>(x, w_enc, xe, h);

  for (int i = 0; i < NB_; i++) {
    int dil = 1 << (i & 7);
    stage1_gemm<<<dim3(13, 8, NBATCH), 256, 0, stream>>>(
        h, w1 + (size_t)i * D_ * C_, s1 + i * C_, b1 + i * C_,
        s2 + i * D_, b2 + i * D_, z);
    stage2_gemm<<<dim3(13, 4, NBATCH), 256, 0, stream>>>(
        h, z, w2 + (size_t)i * C_ * D_, wd + (size_t)i * D_ * 3,
        s3 + i * D_, b3 + i * D_, dil);
  }

  mask_kernel<<<(NBATCH * C_ * L_ + 255) / 256, 256, 0, stream>>>(xe, h, y, NBATCH * C_ * L_);
  dec_kernel<<<(NBATCH * T_ + 255) / 256, 256, 0, stream>>>(y, w_dec, out);
}

// Round 2
// 2620.127 us; speedup vs baseline: 1.9533x; 1.9533x over previous
//
#include <hip/hip_runtime.h>
#include <cstddef>

#define T_     8000
#define L_     803
#define C_     256
#define D_     512
#define NB_    32
#define FK_    20
#define NBATCH 4
#define EPS_   1e-5f

// -------- fold BN params: scale = g*rsqrt(v+eps), bias = b - m*scale --------
__global__ __launch_bounds__(256) void bn_precompute(
    const float* __restrict__ g, const float* __restrict__ b,
    const float* __restrict__ m, const float* __restrict__ v,
    float* __restrict__ scale, float* __restrict__ bias, int n) {
  int i = blockIdx.x * blockDim.x + threadIdx.x;
  if (i >= n) return;
  float s = g[i] * rsqrtf(v[i] + EPS_);
  scale[i] = s;
  bias[i] = b[i] - m[i] * s;
}

// -------- encoder: Conv1d(1->256, k=20, stride=10, pad=20) --------
__global__ __launch_bounds__(256) void enc_kernel(
    const float* __restrict__ x, const float* __restrict__ w_enc,
    float* __restrict__ xe, float* __restrict__ h) {
  int idx = blockIdx.x * blockDim.x + threadIdx.x;
  if (idx >= NBATCH * C_ * L_) return;
  int l = idx % L_;
  int c = (idx / L_) % C_;
  int n = idx / (L_ * C_);
  const float* xn = x + (size_t)n * T_;
  const float* w = w_enc + c * FK_;
  int t0 = l * 10 - 20;
  float acc = 0.f;
#pragma unroll
  for (int k = 0; k < FK_; k++) {
    int t = t0 + k;
    float xv = (t >= 0 && t < T_) ? xn[t] : 0.f;
    acc = fmaf(xv, w[k], acc);
  }
  xe[idx] = acc;
  h[idx] = acc;
}

// -------- stage1: z = BN2( W1 @ BN1(h) )
// GEMM M=512(d) K=256(c) N=803(l), tile 128x64, BK=32, dbuf + reg prefetch
__global__ __launch_bounds__(256) void stage1_gemm(
    const float* __restrict__ h, const float* __restrict__ w1i,
    const float* __restrict__ s1g, const float* __restrict__ b1g,
    const float* __restrict__ s2, const float* __restrict__ b2,
    float* __restrict__ z) {
  const int l0 = blockIdx.x * 64;
  const int d0 = blockIdx.y * 128;
  const int n  = blockIdx.z;
  const int tid = threadIdx.x;

  __shared__ __align__(16) float As[2][32][128];  // [buf][k][m]
  __shared__ __align__(16) float Bs[2][32][64];   // [buf][k][l]
  __shared__ float s1L[C_], b1L[C_];

  s1L[tid] = s1g[tid];   // C_ == 256 == blockDim
  b1L[tid] = b1g[tid];

  float acc[8][4] = {};
  const int tm = (tid & 15) * 4;   // rows tm..tm+3 and tm+64..tm+67
  const int tn = (tid >> 4) * 4;

  const float* hn = h + (size_t)n * (C_ * L_);
  const int colB = tid & 63;
  const int rB0 = tid >> 6;
  const int lB = l0 + colB;
  const bool lv = lB < L_;

  float4 ra[4];
  float  rb[8];

  // prefetch tile 0
#pragma unroll
  for (int q = 0; q < 4; q++) {
    int f = q * 256 + tid;
    ra[q] = *reinterpret_cast<const float4*>(
        w1i + (size_t)(d0 + (f >> 3)) * C_ + ((f & 7) * 4));
  }
#pragma unroll
  for (int q = 0; q < 8; q++) {
    int c = rB0 + q * 4;
    rb[q] = lv ? hn[(size_t)c * L_ + lB] : 0.f;
  }
  __syncthreads();  // param preload visible

  const int NT = C_ / 32;  // 8
  for (int t = 0; t < NT; t++) {
    const int buf = t & 1;
    const int k0 = t * 32;
    // store current regs -> LDS[buf]
#pragma unroll
    for (int q = 0; q < 4; q++) {
      int f = q * 256 + tid;
      int r = f >> 3, c4 = (f & 7) * 4;
      As[buf][c4 + 0][r] = ra[q].x;
      As[buf][c4 + 1][r] = ra[q].y;
      As[buf][c4 + 2][r] = ra[q].z;
      As[buf][c4 + 3][r] = ra[q].w;
    }
#pragma unroll
    for (int q = 0; q < 8; q++) {
      int r = rB0 + q * 4;
      Bs[buf][r][colB] = fmaf(rb[q], s1L[k0 + r], b1L[k0 + r]);
    }
    __syncthreads();
    // prefetch next tile (issued before compute; latency hidden under FMAs)
    if (t + 1 < NT) {
      const int kn = k0 + 32;
#pragma unroll
      for (int q = 0; q < 4; q++) {
        int f = q * 256 + tid;
        ra[q] = *reinterpret_cast<const float4*>(
            w1i + (size_t)(d0 + (f >> 3)) * C_ + kn + ((f & 7) * 4));
      }
#pragma unroll
      for (int q = 0; q < 8; q++) {
        int c = kn + rB0 + q * 4;
        rb[q] = lv ? hn[(size_t)c * L_ + lB] : 0.f;
      }
    }
    // compute from LDS[buf]
#pragma unroll
    for (int kk = 0; kk < 32; kk++) {
      float4 a0 = *reinterpret_cast<const float4*>(&As[buf][kk][tm]);
      float4 a1 = *reinterpret_cast<const float4*>(&As[buf][kk][tm + 64]);
      float4 b  = *reinterpret_cast<const float4*>(&Bs[buf][kk][tn]);
      float av[8] = {a0.x, a0.y, a0.z, a0.w, a1.x, a1.y, a1.z, a1.w};
      float bv[4] = {b.x, b.y, b.z, b.w};
#pragma unroll
      for (int mi = 0; mi < 8; mi++)
#pragma unroll
        for (int ni = 0; ni < 4; ni++)
          acc[mi][ni] = fmaf(av[mi], bv[ni], acc[mi][ni]);
    }
  }

  float* zn = z + (size_t)n * (D_ * L_);
#pragma unroll
  for (int mi = 0; mi < 8; mi++) {
    int d = d0 + ((mi < 4) ? (tm + mi) : (64 + tm + mi - 4));
    float sc = s2[d], bi = b2[d];
#pragma unroll
    for (int ni = 0; ni < 4; ni++) {
      int l = l0 + tn + ni;
      if (l < L_) zn[(size_t)d * L_ + l] = fmaf(acc[mi][ni], sc, bi);
    }
  }
}

// -------- stage2: h += W2 @ BN3( dconv(z) )
// GEMM M=256(c) K=512(d) N=803(l), tile 64x64, BK=32, dbuf + reg prefetch
__global__ __launch_bounds__(256) void stage2_gemm(
    float* __restrict__ h, const float* __restrict__ z,
    const float* __restrict__ w2i, const float* __restrict__ wdi,
    const float* __restrict__ s3, const float* __restrict__ b3,
    int dil) {
  const int l0 = blockIdx.x * 64;
  const int c0 = blockIdx.y * 64;
  const int n  = blockIdx.z;
  const int tid = threadIdx.x;

  __shared__ __align__(16) float As[2][32][64];
  __shared__ __align__(16) float Bs[2][32][64];
  __shared__ float w0L[D_], w1L[D_], w2L[D_], s3L[D_], b3L[D_];

  // preload dconv + BN3 params (wave-uniform broadcast reads later)
#pragma unroll
  for (int i = tid; i < D_; i += 256) {
    w0L[i] = wdi[i * 3 + 0];
    w1L[i] = wdi[i * 3 + 1];
    w2L[i] = wdi[i * 3 + 2];
    s3L[i] = s3[i];
    b3L[i] = b3[i];
  }

  float acc[4][4] = {};
  const int tm = (tid & 15) * 4;
  const int tn = (tid >> 4) * 4;

  const float* zn = z + (size_t)n * (D_ * L_);
  const int colB = tid & 63;
  const int rB0 = tid >> 6;
  const int lB = l0 + colB;
  const bool lv = lB < L_;
  const bool lvm = lv && (lB >= dil);
  const bool lvp = lv && (lB + dil < L_);

  float4 ra[2];
  float  rc[8], rl[8], rr[8];

  // prefetch tile 0
#pragma unroll
  for (int q = 0; q < 2; q++) {
    int f = q * 256 + tid;
    ra[q] = *reinterpret_cast<const float4*>(
        w2i + (size_t)(c0 + (f >> 3)) * D_ + ((f & 7) * 4));
  }
#pragma unroll
  for (int q = 0; q < 8; q++) {
    int d = rB0 + q * 4;
    const float* zd = zn + (size_t)d * L_;
    rc[q] = lv  ? zd[lB]       : 0.f;
    rl[q] = lvm ? zd[lB - dil] : 0.f;
    rr[q] = lvp ? zd[lB + dil] : 0.f;
  }
  __syncthreads();  // params visible

  const int NT = D_ / 32;  // 16
  for (int t = 0; t < NT; t++) {
    const int buf = t & 1;
    const int k0 = t * 32;
#pragma unroll
    for (int q = 0; q < 2; q++) {
      int f = q * 256 + tid;
      int r = f >> 3, c4 = (f & 7) * 4;
      As[buf][c4 + 0][r] = ra[q].x;
      As[buf][c4 + 1][r] = ra[q].y;
      As[buf][c4 + 2][r] = ra[q].z;
      As[buf][c4 + 3][r] = ra[q].w;
    }
#pragma unroll
    for (int q = 0; q < 8; q++) {
      int r = rB0 + q * 4;
      int d = k0 + r;
      float m = rc[q] * w1L[d];
      m = fmaf(rl[q], w0L[d], m);
      m = fmaf(rr[q], w2L[d], m);
      Bs[buf][r][colB] = fmaf(m, s3L[d], b3L[d]);
    }
    __syncthreads();
    if (t + 1 < NT) {
      const int kn = k0 + 32;
#pragma unroll
      for (int q = 0; q < 2; q++) {
        int f = q * 256 + tid;
        ra[q] = *reinterpret_cast<const float4*>(
            w2i + (size_t)(c0 + (f >> 3)) * D_ + kn + ((f & 7) * 4));
      }
#pragma unroll
      for (int q = 0; q < 8; q++) {
        int d = kn + rB0 + q * 4;
        const float* zd = zn + (size_t)d * L_;
        rc[q] = lv  ? zd[lB]       : 0.f;
        rl[q] = lvm ? zd[lB - dil] : 0.f;
        rr[q] = lvp ? zd[lB + dil] : 0.f;
      }
    }
#pragma unroll
    for (int kk = 0; kk < 32; kk++) {
      float4 a = *reinterpret_cast<const float4*>(&As[buf][kk][tm]);
      float4 b = *reinterpret_cast<const float4*>(&Bs[buf][kk][tn]);
      float av[4] = {a.x, a.y, a.z, a.w};
      float bv[4] = {b.x, b.y, b.z, b.w};
#pragma unroll
      for (int mi = 0; mi < 4; mi++)
#pragma unroll
        for (int ni = 0; ni < 4; ni++)
          acc[mi][ni] = fmaf(av[mi], bv[ni], acc[mi][ni]);
    }
  }

  float* hn = h + (size_t)n * (C_ * L_);
#pragma unroll
  for (int mi = 0; mi < 4; mi++) {
    int c = c0 + tm + mi;
#pragma unroll
    for (int ni = 0; ni < 4; ni++) {
      int l = l0 + tn + ni;
      if (l < L_) hn[(size_t)c * L_ + l] += acc[mi][ni];
    }
  }
}

// -------- mask: y = xe * sigmoid(h) --------
__global__ __launch_bounds__(256) void mask_kernel(
    const float* __restrict__ xe, const float* __restrict__ h,
    float* __restrict__ y, int total) {
  int i = blockIdx.x * blockDim.x + threadIdx.x;
  if (i >= total) return;
  float hv = h[i];
  y[i] = xe[i] / (1.f + expf(-hv));
}

// -------- decoder: ConvTranspose1d(C->1, k=20, s=10), slice [20:8020] --------
__global__ __launch_bounds__(256) void dec_kernel(
    const float* __restrict__ y, const float* __restrict__ w_dec,
    float* __restrict__ out) {
  int idx = blockIdx.x * blockDim.x + threadIdx.x;
  if (idx >= NBATCH * T_) return;
  int t = idx % T_;
  int n = idx / T_;
  int tt = t + FK_;
  int l0 = tt / 10;     // in [2, 801]
  int k0 = tt % 10;
  const float* yn = y + (size_t)n * C_ * L_;
  float acc = 0.f;
#pragma unroll 8
  for (int c = 0; c < C_; c++) {
    const float* yr = yn + (size_t)c * L_;
    const float* wr = w_dec + c * FK_;
    acc = fmaf(yr[l0], wr[k0], acc);
    acc = fmaf(yr[l0 - 1], wr[k0 + 10], acc);
  }
  out[idx] = acc;
}

extern "C" void kernel_launch(void* const* d_in, const int* in_sizes, int n_in,
                              void* d_out, int out_size, void* d_ws, size_t ws_size,
                              hipStream_t stream) {
  const float* x     = (const float*)d_in[0];
  const float* w_enc = (const float*)d_in[1];
  const float* w1    = (const float*)d_in[2];
  const float* wd    = (const float*)d_in[3];
  const float* w2    = (const float*)d_in[4];
  const float* w_dec = (const float*)d_in[5];
  const float* bn1g = (const float*)d_in[6],  *bn1b = (const float*)d_in[7],
             * bn1m = (const float*)d_in[8],  *bn1v = (const float*)d_in[9];
  const float* bn2g = (const float*)d_in[10], *bn2b = (const float*)d_in[11],
             * bn2m = (const float*)d_in[12], *bn2v = (const float*)d_in[13];
  const float* bn3g = (const float*)d_in[14], *bn3b = (const float*)d_in[15],
             * bn3m = (const float*)d_in[16], *bn3v = (const float*)d_in[17];
  float* out = (float*)d_out;

  float* ws = (float*)d_ws;
  float* xe = ws;                                  // N*C*L
  float* h  = xe + (size_t)NBATCH * C_ * L_;       // N*C*L
  float* z  = h  + (size_t)NBATCH * C_ * L_;       // N*D*L
  float* s1 = z  + (size_t)NBATCH * D_ * L_;       // NB*C
  float* b1 = s1 + NB_ * C_;
  float* s2 = b1 + NB_ * C_;                       // NB*D
  float* b2 = s2 + NB_ * D_;
  float* s3 = b2 + NB_ * D_;
  float* b3 = s3 + NB_ * D_;
  float* y  = z;  // reuse z region after residual blocks finish

  bn_precompute<<<(NB_ * C_ + 255) / 256, 256, 0, stream>>>(bn1g, bn1b, bn1m, bn1v, s1, b1, NB_ * C_);
  bn_precompute<<<(NB_ * D_ + 255) / 256, 256, 0, stream>>>(bn2g, bn2b, bn2m, bn2v, s2, b2, NB_ * D_);
  bn_precompute<<<(NB_ * D_ + 255) / 256, 256, 0, stream>>>(bn3g, bn3b, bn3m, bn3v, s3, b3, NB_ * D_);

  enc_kernel<<<(NBATCH * C_ * L_ + 255) / 256, 256, 0, stream>>>(x, w_enc, xe, h);

  for (int i = 0; i < NB_; i++) {
    int dil = 1 << (i & 7);
    stage1_gemm<<<dim3(13, 4, NBATCH), 256, 0, stream>>>(
        h, w1 + (size_t)i * D_ * C_, s1 + i * C_, b1 + i * C_,
        s2 + i * D_, b2 + i * D_, z);
    stage2_gemm<<<dim3(13, 4, NBATCH), 256, 0, stream>>>(
        h, z, w2 + (size_t)i * C_ * D_, wd + (size_t)i * D_ * 3,
        s3 + i * D_, b3 + i * D_, dil);
  }

  mask_kernel<<<(NBATCH * C_ * L_ + 255) / 256, 256, 0, stream>>>(xe, h, y, NBATCH * C_ * L_);
  dec_kernel<<<(NBATCH * T_ + 255) / 256, 256, 0, stream>>>(y, w_dec, out);
}

// Round 3
// 1642.564 us; speedup vs baseline: 3.1158x; 1.5951x over previous
//
#include <hip/hip_runtime.h>
#include <cstddef>

#define T_     8000
#define L_     803
#define C_     256
#define D_     512
#define NB_    32
#define FK_    20
#define NBATCH 4
#define EPS_   1e-5f

typedef __attribute__((ext_vector_type(8))) short bf16x8;
typedef __attribute__((ext_vector_type(4))) float f32x4;

__device__ __forceinline__ short f2bf(float x) {
  unsigned u = __float_as_uint(x);
  u += 0x7FFF + ((u >> 16) & 1);   // round-to-nearest-even
  return (short)(u >> 16);
}

// -------- fold all BN params in one launch --------
__global__ __launch_bounds__(256) void bn_precompute_all(
    const float* __restrict__ g1, const float* __restrict__ b1,
    const float* __restrict__ m1, const float* __restrict__ v1,
    const float* __restrict__ g2, const float* __restrict__ b2,
    const float* __restrict__ m2, const float* __restrict__ v2,
    const float* __restrict__ g3, const float* __restrict__ b3,
    const float* __restrict__ m3, const float* __restrict__ v3,
    float* __restrict__ s1, float* __restrict__ o1,
    float* __restrict__ s2, float* __restrict__ o2,
    float* __restrict__ s3, float* __restrict__ o3) {
  int i = blockIdx.x * blockDim.x + threadIdx.x;
  const int NC = NB_ * C_, ND = NB_ * D_;
  if (i < NC) {
    float s = g1[i] * rsqrtf(v1[i] + EPS_);
    s1[i] = s; o1[i] = b1[i] - m1[i] * s;
  } else if (i < NC + ND) {
    int k = i - NC;
    float s = g2[k] * rsqrtf(v2[k] + EPS_);
    s2[k] = s; o2[k] = b2[k] - m2[k] * s;
  } else if (i < NC + 2 * ND) {
    int k = i - NC - ND;
    float s = g3[k] * rsqrtf(v3[k] + EPS_);
    s3[k] = s; o3[k] = b3[k] - m3[k] * s;
  }
}

// -------- encoder: Conv1d(1->256, k=20, stride=10, pad=20) --------
__global__ __launch_bounds__(256) void enc_kernel(
    const float* __restrict__ x, const float* __restrict__ w_enc,
    float* __restrict__ xe, float* __restrict__ h) {
  int idx = blockIdx.x * blockDim.x + threadIdx.x;
  if (idx >= NBATCH * C_ * L_) return;
  int l = idx % L_;
  int c = (idx / L_) % C_;
  int n = idx / (L_ * C_);
  const float* xn = x + (size_t)n * T_;
  const float* w = w_enc + c * FK_;
  int t0 = l * 10 - 20;
  float acc = 0.f;
#pragma unroll
  for (int k = 0; k < FK_; k++) {
    int t = t0 + k;
    float xv = (t >= 0 && t < T_) ? xn[t] : 0.f;
    acc = fmaf(xv, w[k], acc);
  }
  xe[idx] = acc;
  h[idx] = acc;
}

// ============ stage1: z = BN2( W1 @ BN1(h) ), MFMA bf16 ============
// M=512(d) K=256(c) N=803(l); block tile 64x64, 4 waves (2x2), wave 32x32.
// grid: 1-D 448, XCD-grouped: all 8 d-tiles of one (l-tile,n) on same XCD.
__global__ __launch_bounds__(256) void stage1_gemm(
    const float* __restrict__ h, const float* __restrict__ w1i,
    const float* __restrict__ s1g, const float* __restrict__ b1g,
    const float* __restrict__ s2g, const float* __restrict__ b2g,
    float* __restrict__ z) {
  const int gid = blockIdx.x;
  const int xcd = gid & 7, ks = gid >> 3;      // ks in 0..55
  const int j = ks >> 3, y = ks & 7;
  const int g = xcd + 8 * j;                   // group = (x,n) id
  if (g >= 52) return;
  const int x = g % 13, n = g / 13;
  const int l0 = x * 64, d0 = y * 64;
  const int tid = threadIdx.x;

  __shared__ __align__(16) short As[2][64][40];  // [m][k], pad 8 shorts
  __shared__ __align__(16) short Bs[2][64][40];  // [n][k], pad 8 shorts
  __shared__ float s1L[C_], b1L[C_];

  s1L[tid] = s1g[tid];
  b1L[tid] = b1g[tid];

  const float* hn = h + (size_t)n * (C_ * L_);

  // staging assignment
  const int am = tid >> 2, akc = (tid & 3) * 8;   // A: row am, 8 k's
  const int bcol = tid & 63, br0 = (tid >> 6) * 8; // B: col bcol, 8 k's
  const int lB = l0 + bcol;
  const bool lv = lB < L_;

  float4 qa[2][2];
  float qb[2][8];

#pragma unroll
  for (int p = 0; p < 2; p++) {
    const int k0 = p * 32;
    const float* ar = w1i + (size_t)(d0 + am) * C_ + k0 + akc;
    qa[p][0] = *(const float4*)(ar);
    qa[p][1] = *(const float4*)(ar + 4);
#pragma unroll
    for (int q = 0; q < 8; q++)
      qb[p][q] = lv ? hn[(size_t)(k0 + br0 + q) * L_ + lB] : 0.f;
  }
  __syncthreads();  // params visible

  const int wv = tid >> 6, lane = tid & 63;
  const int wr = wv >> 1, wc = wv & 1;
  const int frow = lane & 15, kg = lane >> 4;
  const int arow0 = wr * 32 + frow;
  const int bcol0 = wc * 32 + frow;

  f32x4 acc00 = {}, acc01 = {}, acc10 = {}, acc11 = {};

  const int NT = C_ / 32;  // 8
  for (int t = 0; t < NT; t++) {
    const int buf = t & 1;
    {
      bf16x8 pa, pb;
      pa[0] = f2bf(qa[buf][0].x); pa[1] = f2bf(qa[buf][0].y);
      pa[2] = f2bf(qa[buf][0].z); pa[3] = f2bf(qa[buf][0].w);
      pa[4] = f2bf(qa[buf][1].x); pa[5] = f2bf(qa[buf][1].y);
      pa[6] = f2bf(qa[buf][1].z); pa[7] = f2bf(qa[buf][1].w);
      *(bf16x8*)&As[buf][am][akc] = pa;
#pragma unroll
      for (int q = 0; q < 8; q++) {
        int c = t * 32 + br0 + q;
        pb[q] = f2bf(fmaf(qb[buf][q], s1L[c], b1L[c]));
      }
      *(bf16x8*)&Bs[buf][bcol][br0] = pb;
    }
    __syncthreads();
    if (t + 2 < NT) {
      const int k0 = (t + 2) * 32;
      const float* ar = w1i + (size_t)(d0 + am) * C_ + k0 + akc;
      qa[buf][0] = *(const float4*)(ar);
      qa[buf][1] = *(const float4*)(ar + 4);
#pragma unroll
      for (int q = 0; q < 8; q++)
        qb[buf][q] = lv ? hn[(size_t)(k0 + br0 + q) * L_ + lB] : 0.f;
    }
    bf16x8 af0 = *(bf16x8*)&As[buf][arow0][kg * 8];
    bf16x8 af1 = *(bf16x8*)&As[buf][arow0 + 16][kg * 8];
    bf16x8 bf0 = *(bf16x8*)&Bs[buf][bcol0][kg * 8];
    bf16x8 bf1 = *(bf16x8*)&Bs[buf][bcol0 + 16][kg * 8];
    acc00 = __builtin_amdgcn_mfma_f32_16x16x32_bf16(af0, bf0, acc00, 0, 0, 0);
    acc01 = __builtin_amdgcn_mfma_f32_16x16x32_bf16(af0, bf1, acc01, 0, 0, 0);
    acc10 = __builtin_amdgcn_mfma_f32_16x16x32_bf16(af1, bf0, acc10, 0, 0, 0);
    acc11 = __builtin_amdgcn_mfma_f32_16x16x32_bf16(af1, bf1, acc11, 0, 0, 0);
  }

  // epilogue: z = acc*s2 + b2 ; D layout col=lane&15, row=(lane>>4)*4+j
  float* zn = z + (size_t)n * (D_ * L_);
  const f32x4* accs[4] = {&acc00, &acc01, &acc10, &acc11};
#pragma unroll
  for (int fi = 0; fi < 4; fi++) {
    int fr = fi >> 1, fc = fi & 1;
    int ll = l0 + wc * 32 + fc * 16 + frow;
    if (ll < L_) {
      int dbase = d0 + wr * 32 + fr * 16 + kg * 4;
#pragma unroll
      for (int jj = 0; jj < 4; jj++) {
        int d = dbase + jj;
        zn[(size_t)d * L_ + ll] = fmaf((*accs[fi])[jj], s2g[d], b2g[d]);
      }
    }
  }
}

// ============ stage2: h += W2 @ BN3(dconv(z)), MFMA bf16 ============
// M=256(c) K=512(d) N=803(l); block tile 64x64; grid 1-D 224, XCD-grouped.
__global__ __launch_bounds__(256) void stage2_gemm(
    float* __restrict__ h, const float* __restrict__ z,
    const float* __restrict__ w2i, const float* __restrict__ wdi,
    const float* __restrict__ s3g, const float* __restrict__ b3g,
    int dil) {
  const int gid = blockIdx.x;
  const int xcd = gid & 7, ks = gid >> 3;      // ks in 0..27
  const int j = ks >> 2, y = ks & 3;
  const int g = xcd + 8 * j;
  if (g >= 52) return;
  const int x = g % 13, n = g / 13;
  const int l0 = x * 64, c0 = y * 64;
  const int tid = threadIdx.x;

  __shared__ __align__(16) short As[2][64][40];
  __shared__ __align__(16) short Bs[2][64][40];
  __shared__ float w0L[D_], w1L[D_], w2L[D_], s3L[D_], b3L[D_];

#pragma unroll
  for (int i = tid; i < D_; i += 256) {
    w0L[i] = wdi[i * 3 + 0];
    w1L[i] = wdi[i * 3 + 1];
    w2L[i] = wdi[i * 3 + 2];
    s3L[i] = s3g[i];
    b3L[i] = b3g[i];
  }

  const float* zn = z + (size_t)n * (D_ * L_);

  const int am = tid >> 2, akc = (tid & 3) * 8;
  const int bcol = tid & 63, br0 = (tid >> 6) * 8;
  const int lB = l0 + bcol;
  const bool lv = lB < L_;
  const bool lvm = lv && (lB >= dil);
  const bool lvp = lv && (lB + dil < L_);

  float4 qa[2][2];
  float qc[2][8], ql[2][8], qr[2][8];

#pragma unroll
  for (int p = 0; p < 2; p++) {
    const int k0 = p * 32;
    const float* ar = w2i + (size_t)(c0 + am) * D_ + k0 + akc;
    qa[p][0] = *(const float4*)(ar);
    qa[p][1] = *(const float4*)(ar + 4);
#pragma unroll
    for (int q = 0; q < 8; q++) {
      const float* zd = zn + (size_t)(k0 + br0 + q) * L_;
      qc[p][q] = lv  ? zd[lB]       : 0.f;
      ql[p][q] = lvm ? zd[lB - dil] : 0.f;
      qr[p][q] = lvp ? zd[lB + dil] : 0.f;
    }
  }
  __syncthreads();  // params visible

  const int wv = tid >> 6, lane = tid & 63;
  const int wr = wv >> 1, wc = wv & 1;
  const int frow = lane & 15, kg = lane >> 4;
  const int arow0 = wr * 32 + frow;
  const int bcol0 = wc * 32 + frow;

  f32x4 acc00 = {}, acc01 = {}, acc10 = {}, acc11 = {};

  const int NT = D_ / 32;  // 16
  for (int t = 0; t < NT; t++) {
    const int buf = t & 1;
    {
      bf16x8 pa, pb;
      pa[0] = f2bf(qa[buf][0].x); pa[1] = f2bf(qa[buf][0].y);
      pa[2] = f2bf(qa[buf][0].z); pa[3] = f2bf(qa[buf][0].w);
      pa[4] = f2bf(qa[buf][1].x); pa[5] = f2bf(qa[buf][1].y);
      pa[6] = f2bf(qa[buf][1].z); pa[7] = f2bf(qa[buf][1].w);
      *(bf16x8*)&As[buf][am][akc] = pa;
#pragma unroll
      for (int q = 0; q < 8; q++) {
        int d = t * 32 + br0 + q;
        float m = qc[buf][q] * w1L[d];
        m = fmaf(ql[buf][q], w0L[d], m);
        m = fmaf(qr[buf][q], w2L[d], m);
        pb[q] = f2bf(fmaf(m, s3L[d], b3L[d]));
      }
      *(bf16x8*)&Bs[buf][bcol][br0] = pb;
    }
    __syncthreads();
    if (t + 2 < NT) {
      const int k0 = (t + 2) * 32;
      const float* ar = w2i + (size_t)(c0 + am) * D_ + k0 + akc;
      qa[buf][0] = *(const float4*)(ar);
      qa[buf][1] = *(const float4*)(ar + 4);
#pragma unroll
      for (int q = 0; q < 8; q++) {
        const float* zd = zn + (size_t)(k0 + br0 + q) * L_;
        qc[buf][q] = lv  ? zd[lB]       : 0.f;
        ql[buf][q] = lvm ? zd[lB - dil] : 0.f;
        qr[buf][q] = lvp ? zd[lB + dil] : 0.f;
      }
    }
    bf16x8 af0 = *(bf16x8*)&As[buf][arow0][kg * 8];
    bf16x8 af1 = *(bf16x8*)&As[buf][arow0 + 16][kg * 8];
    bf16x8 bf0 = *(bf16x8*)&Bs[buf][bcol0][kg * 8];
    bf16x8 bf1 = *(bf16x8*)&Bs[buf][bcol0 + 16][kg * 8];
    acc00 = __builtin_amdgcn_mfma_f32_16x16x32_bf16(af0, bf0, acc00, 0, 0, 0);
    acc01 = __builtin_amdgcn_mfma_f32_16x16x32_bf16(af0, bf1, acc01, 0, 0, 0);
    acc10 = __builtin_amdgcn_mfma_f32_16x16x32_bf16(af1, bf0, acc10, 0, 0, 0);
    acc11 = __builtin_amdgcn_mfma_f32_16x16x32_bf16(af1, bf1, acc11, 0, 0, 0);
  }

  float* hn = h + (size_t)n * (C_ * L_);
  const f32x4* accs[4] = {&acc00, &acc01, &acc10, &acc11};
#pragma unroll
  for (int fi = 0; fi < 4; fi++) {
    int fr = fi >> 1, fc = fi & 1;
    int ll = l0 + wc * 32 + fc * 16 + frow;
    if (ll < L_) {
      int cbase = c0 + wr * 32 + fr * 16 + kg * 4;
#pragma unroll
      for (int jj = 0; jj < 4; jj++) {
        int c = cbase + jj;
        hn[(size_t)c * L_ + ll] += (*accs[fi])[jj];
      }
    }
  }
}

// -------- mask: y = xe * sigmoid(h) --------
__global__ __launch_bounds__(256) void mask_kernel(
    const float* __restrict__ xe, const float* __restrict__ h,
    float* __restrict__ y, int total) {
  int i = blockIdx.x * blockDim.x + threadIdx.x;
  if (i >= total) return;
  float hv = h[i];
  y[i] = xe[i] / (1.f + expf(-hv));
}

// -------- decoder: ConvTranspose1d(C->1, k=20, s=10), slice [20:8020] --------
__global__ __launch_bounds__(256) void dec_kernel(
    const float* __restrict__ y, const float* __restrict__ w_dec,
    float* __restrict__ out) {
  int idx = blockIdx.x * blockDim.x + threadIdx.x;
  if (idx >= NBATCH * T_) return;
  int t = idx % T_;
  int n = idx / T_;
  int tt = t + FK_;
  int l0 = tt / 10;     // in [2, 801]
  int k0 = tt % 10;
  const float* yn = y + (size_t)n * C_ * L_;
  float acc = 0.f;
#pragma unroll 8
  for (int c = 0; c < C_; c++) {
    const float* yr = yn + (size_t)c * L_;
    const float* wr = w_dec + c * FK_;
    acc = fmaf(yr[l0], wr[k0], acc);
    acc = fmaf(yr[l0 - 1], wr[k0 + 10], acc);
  }
  out[idx] = acc;
}

extern "C" void kernel_launch(void* const* d_in, const int* in_sizes, int n_in,
                              void* d_out, int out_size, void* d_ws, size_t ws_size,
                              hipStream_t stream) {
  const float* x     = (const float*)d_in[0];
  const float* w_enc = (const float*)d_in[1];
  const float* w1    = (const float*)d_in[2];
  const float* wd    = (const float*)d_in[3];
  const float* w2    = (const float*)d_in[4];
  const float* w_dec = (const float*)d_in[5];
  const float* bn1g = (const float*)d_in[6],  *bn1b = (const float*)d_in[7],
             * bn1m = (const float*)d_in[8],  *bn1v = (const float*)d_in[9];
  const float* bn2g = (const float*)d_in[10], *bn2b = (const float*)d_in[11],
             * bn2m = (const float*)d_in[12], *bn2v = (const float*)d_in[13];
  const float* bn3g = (const float*)d_in[14], *bn3b = (const float*)d_in[15],
             * bn3m = (const float*)d_in[16], *bn3v = (const float*)d_in[17];
  float* out = (float*)d_out;

  float* ws = (float*)d_ws;
  float* xe = ws;                                  // N*C*L
  float* h  = xe + (size_t)NBATCH * C_ * L_;       // N*C*L
  float* z  = h  + (size_t)NBATCH * C_ * L_;       // N*D*L
  float* s1 = z  + (size_t)NBATCH * D_ * L_;       // NB*C
  float* b1 = s1 + NB_ * C_;
  float* s2 = b1 + NB_ * C_;                       // NB*D
  float* b2 = s2 + NB_ * D_;
  float* s3 = b2 + NB_ * D_;
  float* b3 = s3 + NB_ * D_;
  float* y  = z;  // reuse z region after residual blocks finish

  {
    int total = NB_ * C_ + 2 * NB_ * D_;
    bn_precompute_all<<<(total + 255) / 256, 256, 0, stream>>>(
        bn1g, bn1b, bn1m, bn1v, bn2g, bn2b, bn2m, bn2v, bn3g, bn3b, bn3m, bn3v,
        s1, b1, s2, b2, s3, b3);
  }

  enc_kernel<<<(NBATCH * C_ * L_ + 255) / 256, 256, 0, stream>>>(x, w_enc, xe, h);

  for (int i = 0; i < NB_; i++) {
    int dil = 1 << (i & 7);
    stage1_gemm<<<448, 256, 0, stream>>>(
        h, w1 + (size_t)i * D_ * C_, s1 + i * C_, b1 + i * C_,
        s2 + i * D_, b2 + i * D_, z);
    stage2_gemm<<<224, 256, 0, stream>>>(
        h, z, w2 + (size_t)i * C_ * D_, wd + (size_t)i * D_ * 3,
        s3 + i * D_, b3 + i * D_, dil);
  }

  mask_kernel<<<(NBATCH * C_ * L_ + 255) / 256, 256, 0, stream>>>(xe, h, y, NBATCH * C_ * L_);
  dec_kernel<<<(NBATCH * T_ + 255) / 256, 256, 0, stream>>>(y, w_dec, out);
}

// Round 4
// 1084.030 us; speedup vs baseline: 4.7212x; 1.5152x over previous
//
#include <hip/hip_runtime.h>
#include <cstddef>

#define T_     8000
#define L_     803
#define C_     256
#define D_     512
#define NB_    32
#define FK_    20
#define NBATCH 4
#define EPS_   1e-5f

typedef __attribute__((ext_vector_type(8))) short bf16x8;
typedef __attribute__((ext_vector_type(4))) float f32x4;

__device__ __forceinline__ short f2bf(float x) {
  unsigned u = __float_as_uint(x);
  u += 0x7FFF + ((u >> 16) & 1);   // round-to-nearest-even
  return (short)(u >> 16);
}

// -------- fold all BN params in one launch --------
__global__ __launch_bounds__(256) void bn_precompute_all(
    const float* __restrict__ g1, const float* __restrict__ b1,
    const float* __restrict__ m1, const float* __restrict__ v1,
    const float* __restrict__ g2, const float* __restrict__ b2,
    const float* __restrict__ m2, const float* __restrict__ v2,
    const float* __restrict__ g3, const float* __restrict__ b3,
    const float* __restrict__ m3, const float* __restrict__ v3,
    float* __restrict__ s1, float* __restrict__ o1,
    float* __restrict__ s2, float* __restrict__ o2,
    float* __restrict__ s3, float* __restrict__ o3) {
  int i = blockIdx.x * blockDim.x + threadIdx.x;
  const int NC = NB_ * C_, ND = NB_ * D_;
  if (i < NC) {
    float s = g1[i] * rsqrtf(v1[i] + EPS_);
    s1[i] = s; o1[i] = b1[i] - m1[i] * s;
  } else if (i < NC + ND) {
    int k = i - NC;
    float s = g2[k] * rsqrtf(v2[k] + EPS_);
    s2[k] = s; o2[k] = b2[k] - m2[k] * s;
  } else if (i < NC + 2 * ND) {
    int k = i - NC - ND;
    float s = g3[k] * rsqrtf(v3[k] + EPS_);
    s3[k] = s; o3[k] = b3[k] - m3[k] * s;
  }
}

// -------- encoder: Conv1d(1->256, k=20, stride=10, pad=20) --------
__global__ __launch_bounds__(256) void enc_kernel(
    const float* __restrict__ x, const float* __restrict__ w_enc,
    float* __restrict__ xe, float* __restrict__ h) {
  int idx = blockIdx.x * blockDim.x + threadIdx.x;
  if (idx >= NBATCH * C_ * L_) return;
  int l = idx % L_;
  int c = (idx / L_) % C_;
  int n = idx / (L_ * C_);
  const float* xn = x + (size_t)n * T_;
  const float* w = w_enc + c * FK_;
  int t0 = l * 10 - 20;
  float acc = 0.f;
#pragma unroll
  for (int k = 0; k < FK_; k++) {
    int t = t0 + k;
    float xv = (t >= 0 && t < T_) ? xn[t] : 0.f;
    acc = fmaf(xv, w[k], acc);
  }
  xe[idx] = acc;
  h[idx] = acc;
}

// ============ stage1: z = BN2( W1 @ BN1(h) ), MFMA bf16 ============
// M=512(d) K=256(c) N=803(l); block tile 64x64, 4 waves (2x2), wave 32x32.
// grid: 1-D 448, XCD-grouped: all 8 d-tiles of one (l-tile,n) on same XCD.
__global__ __launch_bounds__(256) void stage1_gemm(
    const float* __restrict__ h, const float* __restrict__ w1i,
    const float* __restrict__ s1g, const float* __restrict__ b1g,
    const float* __restrict__ s2g, const float* __restrict__ b2g,
    float* __restrict__ z) {
  const int gid = blockIdx.x;
  const int xcd = gid & 7, ks = gid >> 3;      // ks in 0..55
  const int j = ks >> 3, y = ks & 7;
  const int g = xcd + 8 * j;                   // group = (x,n) id
  if (g >= 52) return;
  const int x = g % 13, n = g / 13;
  const int l0 = x * 64, d0 = y * 64;
  const int tid = threadIdx.x;

  __shared__ __align__(16) short As[2][64][40];  // [m][k], pad 8 shorts
  __shared__ __align__(16) short Bs[2][64][40];  // [n][k], pad 8 shorts
  __shared__ float s1L[C_], b1L[C_];

  s1L[tid] = s1g[tid];
  b1L[tid] = b1g[tid];

  const float* hn = h + (size_t)n * (C_ * L_);

  // staging assignment
  const int am = tid >> 2, akc = (tid & 3) * 8;   // A: row am, 8 k's
  const int bcol = tid & 63, br0 = (tid >> 6) * 8; // B: col bcol, 8 k's
  const int lB = l0 + bcol;
  const bool lv = lB < L_;

  float4 qa[2][2];
  float qb[2][8];

#pragma unroll
  for (int p = 0; p < 2; p++) {
    const int k0 = p * 32;
    const float* ar = w1i + (size_t)(d0 + am) * C_ + k0 + akc;
    qa[p][0] = *(const float4*)(ar);
    qa[p][1] = *(const float4*)(ar + 4);
#pragma unroll
    for (int q = 0; q < 8; q++)
      qb[p][q] = lv ? hn[(size_t)(k0 + br0 + q) * L_ + lB] : 0.f;
  }
  __syncthreads();  // params visible

  const int wv = tid >> 6, lane = tid & 63;
  const int wr = wv >> 1, wc = wv & 1;
  const int frow = lane & 15, kg = lane >> 4;
  const int arow0 = wr * 32 + frow;
  const int bcol0 = wc * 32 + frow;

  f32x4 acc00 = {}, acc01 = {}, acc10 = {}, acc11 = {};

  const int NT = C_ / 32;  // 8
#pragma unroll
  for (int t = 0; t < NT; t++) {
    const int buf = t & 1;
    {
      bf16x8 pa, pb;
      pa[0] = f2bf(qa[buf][0].x); pa[1] = f2bf(qa[buf][0].y);
      pa[2] = f2bf(qa[buf][0].z); pa[3] = f2bf(qa[buf][0].w);
      pa[4] = f2bf(qa[buf][1].x); pa[5] = f2bf(qa[buf][1].y);
      pa[6] = f2bf(qa[buf][1].z); pa[7] = f2bf(qa[buf][1].w);
      *(bf16x8*)&As[buf][am][akc] = pa;
#pragma unroll
      for (int q = 0; q < 8; q++) {
        int c = t * 32 + br0 + q;
        pb[q] = f2bf(fmaf(qb[buf][q], s1L[c], b1L[c]));
      }
      *(bf16x8*)&Bs[buf][bcol][br0] = pb;
    }
    __syncthreads();
    if (t + 2 < NT) {
      const int k0 = (t + 2) * 32;
      const float* ar = w1i + (size_t)(d0 + am) * C_ + k0 + akc;
      qa[buf][0] = *(const float4*)(ar);
      qa[buf][1] = *(const float4*)(ar + 4);
#pragma unroll
      for (int q = 0; q < 8; q++)
        qb[buf][q] = lv ? hn[(size_t)(k0 + br0 + q) * L_ + lB] : 0.f;
    }
    bf16x8 af0 = *(bf16x8*)&As[buf][arow0][kg * 8];
    bf16x8 af1 = *(bf16x8*)&As[buf][arow0 + 16][kg * 8];
    bf16x8 bf0 = *(bf16x8*)&Bs[buf][bcol0][kg * 8];
    bf16x8 bf1 = *(bf16x8*)&Bs[buf][bcol0 + 16][kg * 8];
    acc00 = __builtin_amdgcn_mfma_f32_16x16x32_bf16(af0, bf0, acc00, 0, 0, 0);
    acc01 = __builtin_amdgcn_mfma_f32_16x16x32_bf16(af0, bf1, acc01, 0, 0, 0);
    acc10 = __builtin_amdgcn_mfma_f32_16x16x32_bf16(af1, bf0, acc10, 0, 0, 0);
    acc11 = __builtin_amdgcn_mfma_f32_16x16x32_bf16(af1, bf1, acc11, 0, 0, 0);
  }

  // epilogue: z = acc*s2 + b2 ; D layout col=lane&15, row=(lane>>4)*4+j
  float* zn = z + (size_t)n * (D_ * L_);
  const f32x4* accs[4] = {&acc00, &acc01, &acc10, &acc11};
#pragma unroll
  for (int fi = 0; fi < 4; fi++) {
    int fr = fi >> 1, fc = fi & 1;
    int ll = l0 + wc * 32 + fc * 16 + frow;
    if (ll < L_) {
      int dbase = d0 + wr * 32 + fr * 16 + kg * 4;
#pragma unroll
      for (int jj = 0; jj < 4; jj++) {
        int d = dbase + jj;
        zn[(size_t)d * L_ + ll] = fmaf((*accs[fi])[jj], s2g[d], b2g[d]);
      }
    }
  }
}

// ============ stage2: h += W2 @ BN3(dconv(z)), MFMA bf16 ============
// M=256(c) K=512(d) N=803(l); block tile 64x64; grid 1-D 224, XCD-grouped.
__global__ __launch_bounds__(256) void stage2_gemm(
    float* __restrict__ h, const float* __restrict__ z,
    const float* __restrict__ w2i, const float* __restrict__ wdi,
    const float* __restrict__ s3g, const float* __restrict__ b3g,
    int dil) {
  const int gid = blockIdx.x;
  const int xcd = gid & 7, ks = gid >> 3;      // ks in 0..27
  const int j = ks >> 2, y = ks & 3;
  const int g = xcd + 8 * j;
  if (g >= 52) return;
  const int x = g % 13, n = g / 13;
  const int l0 = x * 64, c0 = y * 64;
  const int tid = threadIdx.x;

  __shared__ __align__(16) short As[2][64][40];
  __shared__ __align__(16) short Bs[2][64][40];
  __shared__ float w0L[D_], w1L[D_], w2L[D_], s3L[D_], b3L[D_];

#pragma unroll
  for (int i = tid; i < D_; i += 256) {
    w0L[i] = wdi[i * 3 + 0];
    w1L[i] = wdi[i * 3 + 1];
    w2L[i] = wdi[i * 3 + 2];
    s3L[i] = s3g[i];
    b3L[i] = b3g[i];
  }

  const float* zn = z + (size_t)n * (D_ * L_);

  const int am = tid >> 2, akc = (tid & 3) * 8;
  const int bcol = tid & 63, br0 = (tid >> 6) * 8;
  const int lB = l0 + bcol;
  const bool lv = lB < L_;
  const bool lvm = lv && (lB >= dil);
  const bool lvp = lv && (lB + dil < L_);

  float4 qa[2][2];
  float qc[2][8], ql[2][8], qr[2][8];

#pragma unroll
  for (int p = 0; p < 2; p++) {
    const int k0 = p * 32;
    const float* ar = w2i + (size_t)(c0 + am) * D_ + k0 + akc;
    qa[p][0] = *(const float4*)(ar);
    qa[p][1] = *(const float4*)(ar + 4);
#pragma unroll
    for (int q = 0; q < 8; q++) {
      const float* zd = zn + (size_t)(k0 + br0 + q) * L_;
      qc[p][q] = lv  ? zd[lB]       : 0.f;
      ql[p][q] = lvm ? zd[lB - dil] : 0.f;
      qr[p][q] = lvp ? zd[lB + dil] : 0.f;
    }
  }
  __syncthreads();  // params visible

  const int wv = tid >> 6, lane = tid & 63;
  const int wr = wv >> 1, wc = wv & 1;
  const int frow = lane & 15, kg = lane >> 4;
  const int arow0 = wr * 32 + frow;
  const int bcol0 = wc * 32 + frow;

  f32x4 acc00 = {}, acc01 = {}, acc10 = {}, acc11 = {};

  const int NT = D_ / 32;  // 16
#pragma unroll
  for (int t = 0; t < NT; t++) {
    const int buf = t & 1;
    {
      bf16x8 pa, pb;
      pa[0] = f2bf(qa[buf][0].x); pa[1] = f2bf(qa[buf][0].y);
      pa[2] = f2bf(qa[buf][0].z); pa[3] = f2bf(qa[buf][0].w);
      pa[4] = f2bf(qa[buf][1].x); pa[5] = f2bf(qa[buf][1].y);
      pa[6] = f2bf(qa[buf][1].z); pa[7] = f2bf(qa[buf][1].w);
      *(bf16x8*)&As[buf][am][akc] = pa;
#pragma unroll
      for (int q = 0; q < 8; q++) {
        int d = t * 32 + br0 + q;
        float m = qc[buf][q] * w1L[d];
        m = fmaf(ql[buf][q], w0L[d], m);
        m = fmaf(qr[buf][q], w2L[d], m);
        pb[q] = f2bf(fmaf(m, s3L[d], b3L[d]));
      }
      *(bf16x8*)&Bs[buf][bcol][br0] = pb;
    }
    __syncthreads();
    if (t + 2 < NT) {
      const int k0 = (t + 2) * 32;
      const float* ar = w2i + (size_t)(c0 + am) * D_ + k0 + akc;
      qa[buf][0] = *(const float4*)(ar);
      qa[buf][1] = *(const float4*)(ar + 4);
#pragma unroll
      for (int q = 0; q < 8; q++) {
        const float* zd = zn + (size_t)(k0 + br0 + q) * L_;
        qc[buf][q] = lv  ? zd[lB]       : 0.f;
        ql[buf][q] = lvm ? zd[lB - dil] : 0.f;
        qr[buf][q] = lvp ? zd[lB + dil] : 0.f;
      }
    }
    bf16x8 af0 = *(bf16x8*)&As[buf][arow0][kg * 8];
    bf16x8 af1 = *(bf16x8*)&As[buf][arow0 + 16][kg * 8];
    bf16x8 bf0 = *(bf16x8*)&Bs[buf][bcol0][kg * 8];
    bf16x8 bf1 = *(bf16x8*)&Bs[buf][bcol0 + 16][kg * 8];
    acc00 = __builtin_amdgcn_mfma_f32_16x16x32_bf16(af0, bf0, acc00, 0, 0, 0);
    acc01 = __builtin_amdgcn_mfma_f32_16x16x32_bf16(af0, bf1, acc01, 0, 0, 0);
    acc10 = __builtin_amdgcn_mfma_f32_16x16x32_bf16(af1, bf0, acc10, 0, 0, 0);
    acc11 = __builtin_amdgcn_mfma_f32_16x16x32_bf16(af1, bf1, acc11, 0, 0, 0);
  }

  float* hn = h + (size_t)n * (C_ * L_);
  const f32x4* accs[4] = {&acc00, &acc01, &acc10, &acc11};
#pragma unroll
  for (int fi = 0; fi < 4; fi++) {
    int fr = fi >> 1, fc = fi & 1;
    int ll = l0 + wc * 32 + fc * 16 + frow;
    if (ll < L_) {
      int cbase = c0 + wr * 32 + fr * 16 + kg * 4;
#pragma unroll
      for (int jj = 0; jj < 4; jj++) {
        int c = cbase + jj;
        hn[(size_t)c * L_ + ll] += (*accs[fi])[jj];
      }
    }
  }
}

// -------- mask: y = xe * sigmoid(h) --------
__global__ __launch_bounds__(256) void mask_kernel(
    const float* __restrict__ xe, const float* __restrict__ h,
    float* __restrict__ y, int total) {
  int i = blockIdx.x * blockDim.x + threadIdx.x;
  if (i >= total) return;
  float hv = h[i];
  y[i] = xe[i] / (1.f + expf(-hv));
}

// -------- decoder: ConvTranspose1d(C->1, k=20, s=10), slice [20:8020] --------
__global__ __launch_bounds__(256) void dec_kernel(
    const float* __restrict__ y, const float* __restrict__ w_dec,
    float* __restrict__ out) {
  int idx = blockIdx.x * blockDim.x + threadIdx.x;
  if (idx >= NBATCH * T_) return;
  int t = idx % T_;
  int n = idx / T_;
  int tt = t + FK_;
  int l0 = tt / 10;     // in [2, 801]
  int k0 = tt % 10;
  const float* yn = y + (size_t)n * C_ * L_;
  float acc = 0.f;
#pragma unroll 8
  for (int c = 0; c < C_; c++) {
    const float* yr = yn + (size_t)c * L_;
    const float* wr = w_dec + c * FK_;
    acc = fmaf(yr[l0], wr[k0], acc);
    acc = fmaf(yr[l0 - 1], wr[k0 + 10], acc);
  }
  out[idx] = acc;
}

extern "C" void kernel_launch(void* const* d_in, const int* in_sizes, int n_in,
                              void* d_out, int out_size, void* d_ws, size_t ws_size,
                              hipStream_t stream) {
  const float* x     = (const float*)d_in[0];
  const float* w_enc = (const float*)d_in[1];
  const float* w1    = (const float*)d_in[2];
  const float* wd    = (const float*)d_in[3];
  const float* w2    = (const float*)d_in[4];
  const float* w_dec = (const float*)d_in[5];
  const float* bn1g = (const float*)d_in[6],  *bn1b = (const float*)d_in[7],
             * bn1m = (const float*)d_in[8],  *bn1v = (const float*)d_in[9];
  const float* bn2g = (const float*)d_in[10], *bn2b = (const float*)d_in[11],
             * bn2m = (const float*)d_in[12], *bn2v = (const float*)d_in[13];
  const float* bn3g = (const float*)d_in[14], *bn3b = (const float*)d_in[15],
             * bn3m = (const float*)d_in[16], *bn3v = (const float*)d_in[17];
  float* out = (float*)d_out;

  float* ws = (float*)d_ws;
  float* xe = ws;                                  // N*C*L
  float* h  = xe + (size_t)NBATCH * C_ * L_;       // N*C*L
  float* z  = h  + (size_t)NBATCH * C_ * L_;       // N*D*L
  float* s1 = z  + (size_t)NBATCH * D_ * L_;       // NB*C
  float* b1 = s1 + NB_ * C_;
  float* s2 = b1 + NB_ * C_;                       // NB*D
  float* b2 = s2 + NB_ * D_;
  float* s3 = b2 + NB_ * D_;
  float* b3 = s3 + NB_ * D_;
  float* y  = z;  // reuse z region after residual blocks finish

  {
    int total = NB_ * C_ + 2 * NB_ * D_;
    bn_precompute_all<<<(total + 255) / 256, 256, 0, stream>>>(
        bn1g, bn1b, bn1m, bn1v, bn2g, bn2b, bn2m, bn2v, bn3g, bn3b, bn3m, bn3v,
        s1, b1, s2, b2, s3, b3);
  }

  enc_kernel<<<(NBATCH * C_ * L_ + 255) / 256, 256, 0, stream>>>(x, w_enc, xe, h);

  for (int i = 0; i < NB_; i++) {
    int dil = 1 << (i & 7);
    stage1_gemm<<<448, 256, 0, stream>>>(
        h, w1 + (size_t)i * D_ * C_, s1 + i * C_, b1 + i * C_,
        s2 + i * D_, b2 + i * D_, z);
    stage2_gemm<<<224, 256, 0, stream>>>(
        h, z, w2 + (size_t)i * C_ * D_, wd + (size_t)i * D_ * 3,
        s3 + i * D_, b3 + i * D_, dil);
  }

  mask_kernel<<<(NBATCH * C_ * L_ + 255) / 256, 256, 0, stream>>>(xe, h, y, NBATCH * C_ * L_);
  dec_kernel<<<(NBATCH * T_ + 255) / 256, 256, 0, stream>>>(y, w_dec, out);
}